// Round 7
// baseline (4111.688 us; speedup 1.0000x reference)
//
#include <hip/hip_runtime.h>
#include <cstdint>
#include <cstddef>

#define B_  64
#define SE_ 128
#define T_  64
#define S_  1024
#define D_  1024
#define V_  32000
#define RB  64   // recurrence blocks

typedef __attribute__((ext_vector_type(8))) short bhalf8;
typedef __attribute__((ext_vector_type(4))) float floatx4;

__device__ __forceinline__ float sigmoidf_(float x){ return 1.0f/(1.0f+__expf(-x)); }

__device__ __forceinline__ ushort f2bf(float f){
  uint32_t u = __float_as_uint(f);
  uint32_t r = (u + 0x7fffu + ((u >> 16) & 1u)) >> 16;
  return (ushort)r;
}
__device__ __forceinline__ float bf2f(ushort h){ return __uint_as_float(((uint32_t)h) << 16); }

__device__ __forceinline__ void glds16(const ushort* g, ushort* l){
  __builtin_amdgcn_global_load_lds((const __attribute__((address_space(1))) void*)g,
                                   (__attribute__((address_space(3))) void*)l, 16, 0, 0);
}

// 16B load that is guaranteed to read at the device coherence point (sc0+sc1):
// two 8-byte SYSTEM-scope relaxed atomic loads. Never served by a stale
// per-XCD L2 line. Requires 8B alignment (we use 16B-aligned addresses).
__device__ __forceinline__ bhalf8 ld_h16_sys(const ushort* p){
  unsigned long long lo = __hip_atomic_load((const unsigned long long*)p,
                                            __ATOMIC_RELAXED, __HIP_MEMORY_SCOPE_SYSTEM);
  unsigned long long hi = __hip_atomic_load((const unsigned long long*)(p + 4),
                                            __ATOMIC_RELAXED, __HIP_MEMORY_SCOPE_SYSTEM);
  union { unsigned long long q[2]; bhalf8 v; } u;
  u.q[0] = lo; u.q[1] = hi;
  return u.v;
}

__device__ __forceinline__ float waveRedSum(float v){
  #pragma unroll
  for (int off = 32; off; off >>= 1) v += __shfl_down(v, off, 64);
  return v;
}

// ---------------- attention path (fp32, small) ----------------

__global__ void k_attnvec(const float* __restrict__ ayi_w, const float* __restrict__ aw_w,
                          float* __restrict__ v){
  int wave = (blockIdx.x * blockDim.x + threadIdx.x) >> 6;
  int lane = threadIdx.x & 63;
  if (wave >= S_) return;
  const float* row = ayi_w + (size_t)wave * S_;
  float acc = 0.f;
  #pragma unroll 4
  for (int s = lane; s < S_; s += 64) acc += row[s] * aw_w[s];
  acc = waveRedSum(acc);
  if (lane == 0) v[wave] = acc;
}

__global__ void k_scores(const float* __restrict__ yts, const float* __restrict__ v,
                         float* __restrict__ scores){
  int wave = (blockIdx.x * blockDim.x + threadIdx.x) >> 6;
  int lane = threadIdx.x & 63;
  const float* row = yts + (size_t)wave * S_;
  float acc = 0.f;
  #pragma unroll 4
  for (int s = lane; s < S_; s += 64) acc += row[s] * v[s];
  acc = waveRedSum(acc);
  if (lane == 0) scores[wave] = acc;
}

__global__ void k_attn(const float* __restrict__ scores, float* __restrict__ attnw,
                       float* __restrict__ outAttn){
  int b = blockIdx.x;
  int e = threadIdx.x;
  __shared__ float sm[128];
  float x = scores[b*SE_ + e];
  sm[e] = x; __syncthreads();
  #pragma unroll
  for (int off = 64; off; off >>= 1){
    if (e < off) sm[e] = fmaxf(sm[e], sm[e+off]);
    __syncthreads();
  }
  float m = sm[0]; __syncthreads();
  float p = __expf(x - m);
  sm[e] = p; __syncthreads();
  #pragma unroll
  for (int off = 64; off; off >>= 1){
    if (e < off) sm[e] += sm[e+off];
    __syncthreads();
  }
  float a = p / sm[0];
  attnw[b*SE_ + e] = a;
  float* dst = outAttn + (size_t)b * T_ * SE_ + e;
  #pragma unroll 4
  for (int t = 0; t < T_; ++t) dst[t*SE_] = a;
}

__global__ void k_ctx(const float* __restrict__ yts, const float* __restrict__ attnw,
                      float* __restrict__ ctx){
  int idx = blockIdx.x * blockDim.x + threadIdx.x;
  int b = idx >> 10, s = idx & (S_-1);
  const float* base = yts + (size_t)b * SE_ * S_ + s;
  const float* a = attnw + b * SE_;
  float acc = 0.f;
  #pragma unroll 8
  for (int e = 0; e < SE_; ++e) acc += a[e] * base[(size_t)e * S_];
  ctx[idx] = acc;
}

// ---------------- conversion / packing ----------------

__global__ void k_transcvt(const float* __restrict__ src, ushort* __restrict__ dst,
                           int K, int N){
  __shared__ float t[32][33];
  int n0 = blockIdx.x * 32, k0 = blockIdx.y * 32;
  for (int r = threadIdx.y; r < 32; r += 8)
    t[r][threadIdx.x] = src[(size_t)(k0 + r) * N + n0 + threadIdx.x];
  __syncthreads();
  for (int r = threadIdx.y; r < 32; r += 8)
    dst[(size_t)(n0 + r) * K + k0 + threadIdx.x] = f2bf(t[threadIdx.x][r]);
}

__global__ void k_cvt(const float* __restrict__ src, ushort* __restrict__ dst, int n4){
  int i = blockIdx.x * blockDim.x + threadIdx.x;
  if (i >= n4) return;
  float4 v = ((const float4*)src)[i];
  ushort4 o; o.x = f2bf(v.x); o.y = f2bf(v.y); o.z = f2bf(v.z); o.w = f2bf(v.w);
  ((ushort4*)dst)[i] = o;
}

__global__ void k_gathercvt(const float* __restrict__ emb, const int* __restrict__ tgt,
                            ushort* __restrict__ Xb){
  int r = blockIdx.x;
  int token = tgt[((r & 63) << 6) + (r >> 6)];
  const float4* src = (const float4*)(emb + (size_t)token * D_);
  ushort* dst = Xb + (size_t)r * D_;
  int i = threadIdx.x;
  float4 v = src[i];
  ushort4 o; o.x = f2bf(v.x); o.y = f2bf(v.y); o.z = f2bf(v.z); o.w = f2bf(v.w);
  ((ushort4*)dst)[i] = o;
}

__global__ void k_packbias(const float* __restrict__ wb0, const float* __restrict__ wb1,
                           const float* __restrict__ wb2, const float* __restrict__ wb3,
                           const float* __restrict__ ub0, const float* __restrict__ ub1,
                           const float* __restrict__ ub2, const float* __restrict__ ub3,
                           float* __restrict__ dst){
  int col = blockIdx.x * blockDim.x + threadIdx.x;
  int g = col >> 10, s = col & 1023;
  const float* wb = (g==0) ? wb0 : (g==1) ? wb1 : (g==2) ? wb2 : wb3;
  const float* ub = (g==0) ? ub0 : (g==1) ? ub1 : (g==2) ? ub2 : ub3;
  dst[col] = wb[s] + ub[s];
}

// ---------------- bf16 MFMA GEMM (m97 structure + XCD-chunked swizzle) ----------------
template<int OUT_MODE>
__global__ __launch_bounds__(256) void k_mfma_gemm(
    const ushort* __restrict__ A, const ushort* __restrict__ BT,
    const float* __restrict__ bias, void* __restrict__ C, int M, int N)
{
  __shared__ ushort As[128*32];
  __shared__ ushort Bs[128*32];
  const int tid = threadIdx.x;
  const int lane = tid & 63, w = tid >> 6;
  const int nwg = gridDim.x * gridDim.y;
  const int L = blockIdx.y * gridDim.x + blockIdx.x;
  const int logical = (L & 7) * (nwg >> 3) + (L >> 3);
  const int by = logical / gridDim.x;
  const int bx = logical - by * gridDim.x;
  const int m0 = by * 128, n0 = bx * 128;
  const int wr = (w >> 1) * 64, wc = (w & 1) * 64;

  const int cr = (lane >> 2);
  const int ck = (lane & 3) * 8;
  const ushort* gA0 = A  + (size_t)(m0 + (2*w)*16   + cr) * 1024 + ck;
  const ushort* gA1 = A  + (size_t)(m0 + (2*w+1)*16 + cr) * 1024 + ck;
  const ushort* gB0 = BT + (size_t)(n0 + (2*w)*16   + cr) * 1024 + ck;
  const ushort* gB1 = BT + (size_t)(n0 + (2*w+1)*16 + cr) * 1024 + ck;
  ushort* lA0 = As + (2*w)*512;   ushort* lA1 = As + (2*w+1)*512;
  ushort* lB0 = Bs + (2*w)*512;   ushort* lB1 = Bs + (2*w+1)*512;

  floatx4 acc[4][4] = {};

  for (int kt = 0; kt < 1024; kt += 32) {
    glds16(gA0 + kt, lA0); glds16(gA1 + kt, lA1);
    glds16(gB0 + kt, lB0); glds16(gB1 + kt, lB1);
    __syncthreads();
    bhalf8 a[4], b[4];
    #pragma unroll
    for (int f = 0; f < 4; ++f) {
      a[f] = *(const bhalf8*)&As[(wr + f*16 + (lane & 15)) * 32 + (lane >> 4) * 8];
      b[f] = *(const bhalf8*)&Bs[(wc + f*16 + (lane & 15)) * 32 + (lane >> 4) * 8];
    }
    #pragma unroll
    for (int i = 0; i < 4; ++i)
      #pragma unroll
      for (int j = 0; j < 4; ++j)
        acc[i][j] = __builtin_amdgcn_mfma_f32_16x16x32_bf16(a[i], b[j], acc[i][j], 0, 0, 0);
    __syncthreads();
  }

  const int crow = (lane >> 4) * 4, ccol = lane & 15;
  #pragma unroll
  for (int i = 0; i < 4; ++i) {
    #pragma unroll
    for (int j = 0; j < 4; ++j) {
      int row = m0 + wr + i*16 + crow;
      int col = n0 + wc + j*16 + ccol;
      float bv = bias ? bias[col] : 0.f;
      #pragma unroll
      for (int r = 0; r < 4; ++r) {
        float v = acc[i][j][r] + bv;
        if (OUT_MODE == 0) {
          ((float*)C)[(size_t)(row + r) * N + col] = v;
        } else if (OUT_MODE == 1) {
          int rr = row + r;
          ((float*)C)[(size_t)(((rr & 63) << 6) + (rr >> 6)) * N + col] = v;
        } else {
          ((ushort*)C)[(size_t)(row + r) * N + col] = f2bf(v);
        }
      }
    }
  }
}

// ---------------- persistent recurrence, SYSTEM-scope coherent cross-XCD sync ----------
// Theory fix (r7): all cross-block data (H, flags) moves through SYSTEM-scope relaxed
// atomics (sc0+sc1 -> coherence-point access). Rounds 3-6 all stalled at ~45us/step
// regardless of sync mechanism because consumer-side AGENT/plain loads could be served
// by the stale, non-coherent per-XCD L2 -- visibility only via ambient-traffic eviction.
// Producer order: H system-stores -> __syncthreads (vmcnt(0): stores MALL-acked) ->
// tid0 system-store ready[j]=t+1. Consumer: wave0 vector-polls 64 slots (system loads),
// then all H reads are system loads (never stale, also fixes a latent replay race).
__global__ __launch_bounds__(512) void k_recur(
    const ushort* __restrict__ WT, const ushort* __restrict__ preb,
    const float* __restrict__ ctx, ushort* __restrict__ Hst,
    uint* __restrict__ ready)
{
  extern __shared__ char smem[];                 // 131072 B: swizzled W panel
  __shared__ float gbuf[4*64*18];                // 18432 B: gate partial sums
  const int tid = threadIdx.x, lane = tid & 63, w = tid >> 6;
  const int j = blockIdx.x;

  // ---- one-time: stage W panel into LDS, swizzled ----
  {
    int c = tid >> 3;                    // 0..63 local gate-col
    int gg = c >> 4, sp = c & 15;
    const ushort* src = WT + ((size_t)(gg*1024 + j*16 + sp) << 10);
    char* dstrow = smem + c*2048;
    int swz = (c & 7) << 4;
    for (int cb = tid & 7; cb < 128; cb += 8) {
      uint4 v = *(const uint4*)(src + cb*8);
      *(uint4*)(dstrow + ((cb*16) ^ swz)) = v;
    }
  }

  // pointwise cell assignment: thread -> (b=pb, s-pair ps,ps+1)
  const int pb = tid >> 3;
  const int ps = (tid & 7) << 1;
  const float ctx0 = ctx[pb*1024 + j*16 + ps];
  const float ctx1 = ctx[pb*1024 + j*16 + ps + 1];

  // mfma geometry
  const int arow = lane & 15;
  const int kof  = (lane >> 4) << 3;             // 0,8,16,24
  const int swzr = (lane & 7) << 4;              // read swizzle
  const int kb0  = (w << 8) + (kof << 1);        // byte offset of k-slice base

  __syncthreads();

  for (int t = 0; t < 64; ++t) {
    // work independent of H[t]: pre-activation loads + gbuf zero (overlaps poll)
    const ushort* prow = preb + (((size_t)(t*64 + pb)) << 12) + j*16 + ps;
    ushort2 pg0 = *(const ushort2*)(prow);
    ushort2 pg1 = *(const ushort2*)(prow + 1024);
    ushort2 pg2 = *(const ushort2*)(prow + 2048);
    ushort2 pg3 = *(const ushort2*)(prow + 3072);
    for (int z = tid; z < 4*64*18; z += 512) gbuf[z] = 0.f;

    // wait for Hst[t]: wave 0 vector-polls all 64 slot flags at the coherence point
    if (t > 0 && w == 0) {
      const uint need = (uint)t;
      for (;;) {
        uint v = __hip_atomic_load(ready + lane, __ATOMIC_RELAXED, __HIP_MEMORY_SCOPE_SYSTEM);
        if (__all(v >= need)) break;
        __builtin_amdgcn_s_sleep(1);
      }
    }
    __syncthreads();
    asm volatile("" ::: "memory");

    // GEMM: this wave's K-slice over 64 rows x 64 gate-cols.
    // A-fragments read with coherence-point (system) loads, all issued up front.
    const ushort* Ab = Hst + ((size_t)t << 16) + (w << 7) + kof;
    bhalf8 af[16];
    #pragma unroll
    for (int u = 0; u < 16; ++u)
      af[u] = ld_h16_sys(Ab + (((u >> 2)*16 + arow) << 10) + (u & 3)*32);
    floatx4 acc[4][4] = {};
    #pragma unroll
    for (int ks = 0; ks < 4; ++ks) {
      #pragma unroll
      for (int gg = 0; gg < 4; ++gg) {
        bhalf8 bf = *(const bhalf8*)(smem + (gg*16 + (lane & 15))*2048
                                          + ((kb0 + ks*64) ^ swzr));
        #pragma unroll
        for (int i = 0; i < 4; ++i)
          acc[i][gg] = __builtin_amdgcn_mfma_f32_16x16x32_bf16(af[(i<<2)|ks], bf, acc[i][gg], 0, 0, 0);
      }
    }

    // reduce 8 K-slices via LDS float atomics (stride 18: <=2-way banks)
    #pragma unroll
    for (int i = 0; i < 4; ++i) {
      #pragma unroll
      for (int gg = 0; gg < 4; ++gg) {
        #pragma unroll
        for (int r = 0; r < 4; ++r) {
          int row = i*16 + ((lane >> 4) << 2) + r;
          atomicAdd(&gbuf[(gg*64 + row)*18 + (lane & 15)], acc[i][gg][r]);
        }
      }
    }
    __syncthreads();

    // fused pointwise LSTM cell for 2 cells; system store to Hst[t+1]
    {
      float f0 = gbuf[(0*64 + pb)*18 + ps]     + bf2f(pg0.x);
      float f1 = gbuf[(0*64 + pb)*18 + ps + 1] + bf2f(pg0.y);
      float i0 = gbuf[(1*64 + pb)*18 + ps]     + bf2f(pg1.x);
      float i1 = gbuf[(1*64 + pb)*18 + ps + 1] + bf2f(pg1.y);
      float o0 = gbuf[(2*64 + pb)*18 + ps]     + bf2f(pg2.x);
      float o1 = gbuf[(2*64 + pb)*18 + ps + 1] + bf2f(pg2.y);
      float c0 = gbuf[(3*64 + pb)*18 + ps]     + bf2f(pg3.x);
      float c1 = gbuf[(3*64 + pb)*18 + ps + 1] + bf2f(pg3.y);
      float ct0 = sigmoidf_(f0) * ctx0 + sigmoidf_(i0) * tanhf(c0);
      float ct1 = sigmoidf_(f1) * ctx1 + sigmoidf_(i1) * tanhf(c1);
      float h0 = sigmoidf_(o0) * tanhf(ct0);
      float h1 = sigmoidf_(o1) * tanhf(ct1);
      uint hv = (uint)f2bf(h0) | ((uint)f2bf(h1) << 16);
      uint* dst = (uint*)(Hst + (((size_t)(t+1)) << 16) + pb*1024 + j*16 + ps);
      __hip_atomic_store(dst, hv, __ATOMIC_RELAXED, __HIP_MEMORY_SCOPE_SYSTEM);
    }
    __syncthreads();   // every wave drains its own vmcnt(0): H stores MALL-acked
    if (tid == 0)
      __hip_atomic_store(ready + j, (uint)(t + 1), __ATOMIC_RELAXED, __HIP_MEMORY_SCOPE_SYSTEM);
  }
}

// ---------------- single-pass row softmax over V=32000 (row staged in LDS) ----------------
__global__ __launch_bounds__(256) void k_softmaxV(float* __restrict__ out){
  extern __shared__ float rowbuf[];
  int r = blockIdx.x;
  float4* p = (float4*)(out + (size_t)r * V_);
  float4* rb = (float4*)rowbuf;
  int tid = threadIdx.x;
  float m = -1e30f, ssum = 0.f;
  for (int i = tid; i < 8000; i += 256) {
    float4 v = p[i];
    rb[i] = v;
    float m4 = fmaxf(fmaxf(v.x, v.y), fmaxf(v.z, v.w));
    float mn = fmaxf(m, m4);
    ssum = ssum * __expf(m - mn)
         + __expf(v.x - mn) + __expf(v.y - mn) + __expf(v.z - mn) + __expf(v.w - mn);
    m = mn;
  }
  __shared__ float ms[256], ss[256];
  ms[tid] = m; ss[tid] = ssum; __syncthreads();
  #pragma unroll
  for (int off = 128; off; off >>= 1) {
    if (tid < off) {
      float m2 = fmaxf(ms[tid], ms[tid+off]);
      ss[tid] = ss[tid]*__expf(ms[tid]-m2) + ss[tid+off]*__expf(ms[tid+off]-m2);
      ms[tid] = m2;
    }
    __syncthreads();
  }
  float M = ms[0];
  float inv = 1.0f / ss[0];
  for (int i = tid; i < 8000; i += 256) {
    float4 v = rb[i];
    v.x = __expf(v.x - M) * inv; v.y = __expf(v.y - M) * inv;
    v.z = __expf(v.z - M) * inv; v.w = __expf(v.w - M) * inv;
    p[i] = v;
  }
}

// ---------------- host ----------------

extern "C" void kernel_launch(void* const* d_in, const int* in_sizes, int n_in,
                              void* d_out, int out_size, void* d_ws, size_t ws_size,
                              hipStream_t stream){
  const float* yts   = (const float*)d_in[0];
  const float* enc_h = (const float*)d_in[1];
  const int*   tgt   = (const int*)d_in[2];
  const float* emb   = (const float*)d_in[3];
  const float* ayi_w = (const float*)d_in[6];
  const float* aw_w  = (const float*)d_in[8];
  const float* wf_w = (const float*)d_in[10]; const float* wf_b = (const float*)d_in[11];
  const float* uf_w = (const float*)d_in[12]; const float* uf_b = (const float*)d_in[13];
  const float* wi_w = (const float*)d_in[14]; const float* wi_b = (const float*)d_in[15];
  const float* ui_w = (const float*)d_in[16]; const float* ui_b = (const float*)d_in[17];
  const float* wo_w = (const float*)d_in[18]; const float* wo_b = (const float*)d_in[19];
  const float* uo_w = (const float*)d_in[20]; const float* uo_b = (const float*)d_in[21];
  const float* wc_w = (const float*)d_in[22]; const float* wc_b = (const float*)d_in[23];
  const float* uc_w = (const float*)d_in[24]; const float* uc_b = (const float*)d_in[25];
  const float* xh_w = (const float*)d_in[26]; const float* xh_b = (const float*)d_in[27];
  const float* cls_w= (const float*)d_in[28]; const float* cls_b= (const float*)d_in[29];

  float* out = (float*)d_out;
  float* outAttn = out + (size_t)B_ * T_ * V_;

  char* wsb = (char*)d_ws;
  size_t off = 0;
  auto alloc = [&](size_t bytes)->char*{
    char* p = wsb + off; off += (bytes + 255) & ~(size_t)255; return p;
  };
  ushort* clsT  = (ushort*)alloc((size_t)V_ * 1024 * 2);
  ushort* xhT   = (ushort*)alloc((size_t)1024 * 1024 * 2);
  ushort* WcatT = (ushort*)alloc((size_t)4096 * 1024 * 2);
  ushort* UcatT = (ushort*)alloc((size_t)4096 * 1024 * 2);
  float*  biasU = (float*)alloc(4096 * 4);
  float*  vvec  = (float*)alloc(S_ * 4);
  float*  scores= (float*)alloc(B_ * SE_ * 4);
  float*  attnw = (float*)alloc(B_ * SE_ * 4);
  float*  ctx   = (float*)alloc(B_ * S_ * 4);
  uint*   ready = (uint*)alloc(256);            // 64 slot flags, packed
  ushort* Xb    = (ushort*)alloc((size_t)4096 * 1024 * 2);
  ushort* preb  = (ushort*)alloc((size_t)4096 * 4096 * 2);
  ushort* Hst   = (ushort*)alloc((size_t)65 * 64 * 1024 * 2);
  if (off > ws_size) return;
  ushort* Zb = Xb; // Xb dead after pre-GEMM; reuse for Z

  dim3 tb(32, 8);
  k_transcvt<<<dim3(V_/32, 32), tb, 0, stream>>>(cls_w, clsT, 1024, V_);
  k_transcvt<<<dim3(32, 32), tb, 0, stream>>>(xh_w, xhT, 1024, 1024);
  k_transcvt<<<dim3(32, 32), tb, 0, stream>>>(wf_w, WcatT + 0u*1048576u, 1024, 1024);
  k_transcvt<<<dim3(32, 32), tb, 0, stream>>>(wi_w, WcatT + 1u*1048576u, 1024, 1024);
  k_transcvt<<<dim3(32, 32), tb, 0, stream>>>(wo_w, WcatT + 2u*1048576u, 1024, 1024);
  k_transcvt<<<dim3(32, 32), tb, 0, stream>>>(wc_w, WcatT + 3u*1048576u, 1024, 1024);
  k_transcvt<<<dim3(32, 32), tb, 0, stream>>>(uf_w, UcatT + 0u*1048576u, 1024, 1024);
  k_transcvt<<<dim3(32, 32), tb, 0, stream>>>(ui_w, UcatT + 1u*1048576u, 1024, 1024);
  k_transcvt<<<dim3(32, 32), tb, 0, stream>>>(uo_w, UcatT + 2u*1048576u, 1024, 1024);
  k_transcvt<<<dim3(32, 32), tb, 0, stream>>>(uc_w, UcatT + 3u*1048576u, 1024, 1024);
  k_packbias<<<16, 256, 0, stream>>>(wf_b, wi_b, wo_b, wc_b, uf_b, ui_b, uo_b, uc_b, biasU);
  k_cvt<<<64, 256, 0, stream>>>(enc_h, Hst, 16384);
  k_gathercvt<<<4096, 256, 0, stream>>>(emb, tgt, Xb);

  k_attnvec<<<256, 256, 0, stream>>>(ayi_w, aw_w, vvec);
  k_scores<<<2048, 256, 0, stream>>>(yts, vvec, scores);
  k_attn<<<64, 128, 0, stream>>>(scores, attnw, outAttn);
  k_ctx<<<256, 256, 0, stream>>>(yts, attnw, ctx);

  // pre = X @ Ucat + biasU  -> bf16 [4096][4096]
  k_mfma_gemm<2><<<dim3(32, 32), 256, 0, stream>>>(Xb, UcatT, biasU, preb, 4096, 4096);

  // persistent recurrence: system-scope coherent flag sync (cooperative for co-residency)
  hipMemsetAsync(ready, 0, 256, stream);
  {
    void* args[] = { (void*)&WcatT, (void*)&preb, (void*)&ctx, (void*)&Hst, (void*)&ready };
    hipLaunchCooperativeKernel((void*)k_recur, dim3(RB), dim3(512), args, 131072, stream);
  }

  // Z = H @ xh_w + xh_b  -> bf16 [4096][1024]
  k_mfma_gemm<2><<<dim3(8, 32), 256, 0, stream>>>(Hst + 65536, xhT, xh_b, Zb, 4096, 1024);
  // out = Z @ cls_w + cls_b (rows remapped t*64+b -> b*64+t), f32
  k_mfma_gemm<1><<<dim3(V_/128, 32), 256, 0, stream>>>(Zb, clsT, cls_b, out, 4096, V_);
  // single-pass softmax, row staged in LDS
  k_softmaxV<<<4096, 256, 128000, stream>>>(out);
}

// Round 8
// 4099.699 us; speedup vs baseline: 1.0029x; 1.0029x over previous
//
#include <hip/hip_runtime.h>
#include <cstdint>
#include <cstddef>

#define B_  64
#define SE_ 128
#define T_  64
#define S_  1024
#define D_  1024
#define V_  32000
#define HSLOT 65536ull   // one H step: 64*1024 bf16 elems

typedef __attribute__((ext_vector_type(8))) short bhalf8;
typedef __attribute__((ext_vector_type(4))) float floatx4;

__device__ __forceinline__ float sigmoidf_(float x){ return 1.0f/(1.0f+__expf(-x)); }

__device__ __forceinline__ ushort f2bf(float f){
  uint32_t u = __float_as_uint(f);
  uint32_t r = (u + 0x7fffu + ((u >> 16) & 1u)) >> 16;
  return (ushort)r;
}
__device__ __forceinline__ float bf2f(ushort h){ return __uint_as_float(((uint32_t)h) << 16); }

__device__ __forceinline__ void glds16(const ushort* g, ushort* l){
  __builtin_amdgcn_global_load_lds((const __attribute__((address_space(1))) void*)g,
                                   (__attribute__((address_space(3))) void*)l, 16, 0, 0);
}

__device__ __forceinline__ float waveRedSum(float v){
  #pragma unroll
  for (int off = 32; off; off >>= 1) v += __shfl_down(v, off, 64);
  return v;
}

// ---------------- attention path (fp32, small) ----------------

__global__ void k_attnvec(const float* __restrict__ ayi_w, const float* __restrict__ aw_w,
                          float* __restrict__ v){
  int wave = (blockIdx.x * blockDim.x + threadIdx.x) >> 6;
  int lane = threadIdx.x & 63;
  if (wave >= S_) return;
  const float* row = ayi_w + (size_t)wave * S_;
  float acc = 0.f;
  #pragma unroll 4
  for (int s = lane; s < S_; s += 64) acc += row[s] * aw_w[s];
  acc = waveRedSum(acc);
  if (lane == 0) v[wave] = acc;
}

__global__ void k_scores(const float* __restrict__ yts, const float* __restrict__ v,
                         float* __restrict__ scores){
  int wave = (blockIdx.x * blockDim.x + threadIdx.x) >> 6;
  int lane = threadIdx.x & 63;
  const float* row = yts + (size_t)wave * S_;
  float acc = 0.f;
  #pragma unroll 4
  for (int s = lane; s < S_; s += 64) acc += row[s] * v[s];
  acc = waveRedSum(acc);
  if (lane == 0) scores[wave] = acc;
}

__global__ void k_attn(const float* __restrict__ scores, float* __restrict__ attnw,
                       float* __restrict__ outAttn){
  int b = blockIdx.x;
  int e = threadIdx.x;
  __shared__ float sm[128];
  float x = scores[b*SE_ + e];
  sm[e] = x; __syncthreads();
  #pragma unroll
  for (int off = 64; off; off >>= 1){
    if (e < off) sm[e] = fmaxf(sm[e], sm[e+off]);
    __syncthreads();
  }
  float m = sm[0]; __syncthreads();
  float p = __expf(x - m);
  sm[e] = p; __syncthreads();
  #pragma unroll
  for (int off = 64; off; off >>= 1){
    if (e < off) sm[e] += sm[e+off];
    __syncthreads();
  }
  float a = p / sm[0];
  attnw[b*SE_ + e] = a;
  float* dst = outAttn + (size_t)b * T_ * SE_ + e;
  #pragma unroll 4
  for (int t = 0; t < T_; ++t) dst[t*SE_] = a;
}

__global__ void k_ctx(const float* __restrict__ yts, const float* __restrict__ attnw,
                      float* __restrict__ ctx){
  int idx = blockIdx.x * blockDim.x + threadIdx.x;
  int b = idx >> 10, s = idx & (S_-1);
  const float* base = yts + (size_t)b * SE_ * S_ + s;
  const float* a = attnw + b * SE_;
  float acc = 0.f;
  #pragma unroll 8
  for (int e = 0; e < SE_; ++e) acc += a[e] * base[(size_t)e * S_];
  ctx[idx] = acc;
}

// ---------------- conversion / packing ----------------

__global__ void k_transcvt(const float* __restrict__ src, ushort* __restrict__ dst,
                           int K, int N){
  __shared__ float t[32][33];
  int n0 = blockIdx.x * 32, k0 = blockIdx.y * 32;
  for (int r = threadIdx.y; r < 32; r += 8)
    t[r][threadIdx.x] = src[(size_t)(k0 + r) * N + n0 + threadIdx.x];
  __syncthreads();
  for (int r = threadIdx.y; r < 32; r += 8)
    dst[(size_t)(n0 + r) * K + k0 + threadIdx.x] = f2bf(t[threadIdx.x][r]);
}

// enc_h f32 -> bf16, replicated into slot 0 of each XCD group's H buffer
__global__ void k_cvtrep(const float* __restrict__ src, ushort* __restrict__ Hgs){
  int i = blockIdx.x * blockDim.x + threadIdx.x;   // 16384 float4 groups
  float4 v = ((const float4*)src)[i];
  ushort4 o; o.x = f2bf(v.x); o.y = f2bf(v.y); o.z = f2bf(v.z); o.w = f2bf(v.w);
  #pragma unroll
  for (int g = 0; g < 8; ++g) {
    size_t gbase = (g == 0) ? 0ull : (65ull + (size_t)(g-1)*8ull) * HSLOT;
    ((ushort4*)(Hgs + gbase))[i] = o;
  }
}

__global__ void k_gathercvt(const float* __restrict__ emb, const int* __restrict__ tgt,
                            ushort* __restrict__ Xb){
  int r = blockIdx.x;
  int token = tgt[((r & 63) << 6) + (r >> 6)];
  const float4* src = (const float4*)(emb + (size_t)token * D_);
  ushort* dst = Xb + (size_t)r * D_;
  int i = threadIdx.x;
  float4 v = src[i];
  ushort4 o; o.x = f2bf(v.x); o.y = f2bf(v.y); o.z = f2bf(v.z); o.w = f2bf(v.w);
  ((ushort4*)dst)[i] = o;
}

__global__ void k_packbias(const float* __restrict__ wb0, const float* __restrict__ wb1,
                           const float* __restrict__ wb2, const float* __restrict__ wb3,
                           const float* __restrict__ ub0, const float* __restrict__ ub1,
                           const float* __restrict__ ub2, const float* __restrict__ ub3,
                           float* __restrict__ dst){
  int col = blockIdx.x * blockDim.x + threadIdx.x;
  int g = col >> 10, s = col & 1023;
  const float* wb = (g==0) ? wb0 : (g==1) ? wb1 : (g==2) ? wb2 : wb3;
  const float* ub = (g==0) ? ub0 : (g==1) ? ub1 : (g==2) ? ub2 : ub3;
  dst[col] = wb[s] + ub[s];
}

// ---------------- bf16 MFMA GEMM (m97 structure + XCD-chunked swizzle) ----------------
template<int OUT_MODE>
__global__ __launch_bounds__(256) void k_mfma_gemm(
    const ushort* __restrict__ A, const ushort* __restrict__ BT,
    const float* __restrict__ bias, void* __restrict__ C, int M, int N)
{
  __shared__ ushort As[128*32];
  __shared__ ushort Bs[128*32];
  const int tid = threadIdx.x;
  const int lane = tid & 63, w = tid >> 6;
  const int nwg = gridDim.x * gridDim.y;
  const int L = blockIdx.y * gridDim.x + blockIdx.x;
  const int logical = (L & 7) * (nwg >> 3) + (L >> 3);
  const int by = logical / gridDim.x;
  const int bx = logical - by * gridDim.x;
  const int m0 = by * 128, n0 = bx * 128;
  const int wr = (w >> 1) * 64, wc = (w & 1) * 64;

  const int cr = (lane >> 2);
  const int ck = (lane & 3) * 8;
  const ushort* gA0 = A  + (size_t)(m0 + (2*w)*16   + cr) * 1024 + ck;
  const ushort* gA1 = A  + (size_t)(m0 + (2*w+1)*16 + cr) * 1024 + ck;
  const ushort* gB0 = BT + (size_t)(n0 + (2*w)*16   + cr) * 1024 + ck;
  const ushort* gB1 = BT + (size_t)(n0 + (2*w+1)*16 + cr) * 1024 + ck;
  ushort* lA0 = As + (2*w)*512;   ushort* lA1 = As + (2*w+1)*512;
  ushort* lB0 = Bs + (2*w)*512;   ushort* lB1 = Bs + (2*w+1)*512;

  floatx4 acc[4][4] = {};

  for (int kt = 0; kt < 1024; kt += 32) {
    glds16(gA0 + kt, lA0); glds16(gA1 + kt, lA1);
    glds16(gB0 + kt, lB0); glds16(gB1 + kt, lB1);
    __syncthreads();
    bhalf8 a[4], b[4];
    #pragma unroll
    for (int f = 0; f < 4; ++f) {
      a[f] = *(const bhalf8*)&As[(wr + f*16 + (lane & 15)) * 32 + (lane >> 4) * 8];
      b[f] = *(const bhalf8*)&Bs[(wc + f*16 + (lane & 15)) * 32 + (lane >> 4) * 8];
    }
    #pragma unroll
    for (int i = 0; i < 4; ++i)
      #pragma unroll
      for (int j = 0; j < 4; ++j)
        acc[i][j] = __builtin_amdgcn_mfma_f32_16x16x32_bf16(a[i], b[j], acc[i][j], 0, 0, 0);
    __syncthreads();
  }

  const int crow = (lane >> 4) * 4, ccol = lane & 15;
  #pragma unroll
  for (int i = 0; i < 4; ++i) {
    #pragma unroll
    for (int j = 0; j < 4; ++j) {
      int row = m0 + wr + i*16 + crow;
      int col = n0 + wc + j*16 + ccol;
      float bv = bias ? bias[col] : 0.f;
      #pragma unroll
      for (int r = 0; r < 4; ++r) {
        float v = acc[i][j][r] + bv;
        if (OUT_MODE == 0) {
          ((float*)C)[(size_t)(row + r) * N + col] = v;
        } else if (OUT_MODE == 1) {
          int rr = row + r;
          ((float*)C)[(size_t)(((rr & 63) << 6) + (rr >> 6)) * N + col] = v;
        } else {
          ((ushort*)C)[(size_t)(row + r) * N + col] = f2bf(v);
        }
      }
    }
  }
}

// ---------------- XCD-local replicated recurrence (NO cross-XCD traffic) -------------
// 256 blocks x 512 threads, 1 block/CU (84KB LDS forces it). Each block reads its
// physical XCD via s_getreg(HW_REG_XCC_ID) and takes a per-XCD rank r in [0,32).
// Each XCD group of 32 blocks REPLICATES the full recurrence: block r owns s-cols
// [r*32,(r+1)*32) x 4 gates = 128 gate-cols, whose W columns live PERMANENTLY in
// VGPRs (32 bhalf8 frags = 128 VGPR/lane; wave w: gate w>>1, 16-col half w&1).
// H flows only through the XCD-local L2: plain write-through stores, fresh-address
// reads (group 0: 65-slot history for the epilogue; groups 1-7: 8-slot ring), and
// AGENT-scope slot flags. 3 barriers + 1 local-L2 poll per step.
__global__ __launch_bounds__(512) void k_recur(
    const ushort* __restrict__ WT, const ushort* __restrict__ preb,
    const float* __restrict__ ctx, ushort* __restrict__ Hgs,
    uint* __restrict__ ready, uint* __restrict__ cnt)
{
  extern __shared__ char smem[];               // >=84KB (occupancy limiter)
  float* gbuf = (float*)smem;                  // [64][132] f32 = 33792 B
  __shared__ uint sgrp, srank;
  const int tid = threadIdx.x, lane = tid & 63, w = tid >> 6;

  if (tid == 0) {
    uint xcc;
    asm volatile("s_getreg_b32 %0, hwreg(HW_REG_XCC_ID, 0, 32)" : "=s"(xcc));
    xcc &= 7u;
    sgrp = xcc;
    srank = atomicAdd(&cnt[xcc], 1u) & 31u;
  }
  __syncthreads();
  const int grp = (int)sgrp, r = (int)srank;
  const size_t gbase = (grp == 0) ? 0ull : (65ull + (size_t)(grp-1)*8ull) * HSLOT;

  // ---- W columns into VGPRs: wave w -> gate g=w>>1, 16-col half s16=w&1 ----
  const int gate = w >> 1, s16 = w & 1;
  const int colg = (gate << 10) + (r << 5) + (s16 << 4) + (lane & 15); // WT row
  const ushort* wrow = WT + ((size_t)colg << 10) + ((lane >> 4) << 3);
  bhalf8 wfrag[32];
  #pragma unroll
  for (int kk = 0; kk < 32; ++kk)
    wfrag[kk] = *(const bhalf8*)(wrow + kk*32);

  // pointwise cell assignment: thread -> (b, 4 consecutive s)
  const int pb = tid >> 3;
  const int sl4 = (tid & 7) << 2;
  const float4 ctx4 = *(const float4*)(ctx + (pb << 10) + (r << 5) + sl4);

  const int arow = lane & 15;
  const int aoff = (lane >> 4) << 3;
  const int colw = (w << 4) + (lane & 15);     // gbuf col 0..127
  uint* myflags = ready + grp * 64;

  #pragma unroll 1
  for (int t = 0; t < 64; ++t) {
    // pre-activation loads (independent of H) — overlap the wait
    const ushort* prow = preb + (((size_t)(t*64 + pb)) << 12) + (r << 5) + sl4;
    ushort4 pf = *(const ushort4*)(prow);
    ushort4 pi = *(const ushort4*)(prow + 1024);
    ushort4 po = *(const ushort4*)(prow + 2048);
    ushort4 pc = *(const ushort4*)(prow + 3072);

    // wait for this XCD's H[t]: wave0 polls the 32 group flags in the LOCAL L2
    if (t > 0) {
      if (w == 0) {
        const uint need = (uint)t;
        for (;;) {
          uint v = __hip_atomic_load(myflags + (lane & 31), __ATOMIC_RELAXED,
                                     __HIP_MEMORY_SCOPE_AGENT);
          if (__all(v >= need)) break;
          __builtin_amdgcn_s_sleep(1);
        }
      }
      __syncthreads();
      asm volatile("" ::: "memory");
    }

    // GEMM: C[64 rows][16 cols] per wave, full K=1024 from VGPR-resident W
    const ushort* Hrd = Hgs + gbase + (size_t)(grp == 0 ? t : (t & 7)) * HSLOT;
    floatx4 acc[4] = {};
    #pragma unroll
    for (int kk = 0; kk < 32; ++kk) {
      #pragma unroll
      for (int i = 0; i < 4; ++i) {
        bhalf8 a = *(const bhalf8*)(Hrd + ((i*16 + arow) << 10) + kk*32 + aoff);
        acc[i] = __builtin_amdgcn_mfma_f32_16x16x32_bf16(a, wfrag[kk], acc[i], 0, 0, 0);
      }
    }

    // exchange gates through LDS (each cell written exactly once, no atomics)
    #pragma unroll
    for (int i = 0; i < 4; ++i) {
      #pragma unroll
      for (int rr = 0; rr < 4; ++rr)
        gbuf[(i*16 + ((lane >> 4) << 2) + rr)*132 + colw] = acc[i][rr];
    }
    __syncthreads();

    // fused pointwise LSTM cell (4 cells/thread); plain store to local H[t+1]
    {
      const float* gb = gbuf + pb*132;
      float h[4];
      const ushort* pfp = (const ushort*)&pf; const ushort* pip = (const ushort*)&pi;
      const ushort* pop = (const ushort*)&po; const ushort* pcp = (const ushort*)&pc;
      const float* cxp = (const float*)&ctx4;
      #pragma unroll
      for (int c = 0; c < 4; ++c) {
        float fv = gb[      sl4 + c] + bf2f(pfp[c]);
        float iv = gb[32  + sl4 + c] + bf2f(pip[c]);
        float ov = gb[64  + sl4 + c] + bf2f(pop[c]);
        float cv = gb[96  + sl4 + c] + bf2f(pcp[c]);
        float ct = sigmoidf_(fv) * cxp[c] + sigmoidf_(iv) * tanhf(cv);
        h[c] = sigmoidf_(ov) * tanhf(ct);
      }
      ushort4 hv; hv.x = f2bf(h[0]); hv.y = f2bf(h[1]); hv.z = f2bf(h[2]); hv.w = f2bf(h[3]);
      ushort* Hwr = Hgs + gbase + (size_t)(grp == 0 ? (t+1) : ((t+1) & 7)) * HSLOT;
      *(ushort4*)(Hwr + (pb << 10) + (r << 5) + sl4) = hv;
    }
    __syncthreads();   // drains vmcnt(0): H stores are in the local L2
    if (tid == 0)
      __hip_atomic_store(myflags + r, (uint)(t + 1), __ATOMIC_RELAXED,
                         __HIP_MEMORY_SCOPE_AGENT);
  }
}

// ---------------- single-pass row softmax over V=32000 (row staged in LDS) ----------------
__global__ __launch_bounds__(256) void k_softmaxV(float* __restrict__ out){
  extern __shared__ float rowbuf[];
  int r = blockIdx.x;
  float4* p = (float4*)(out + (size_t)r * V_);
  float4* rb = (float4*)rowbuf;
  int tid = threadIdx.x;
  float m = -1e30f, ssum = 0.f;
  for (int i = tid; i < 8000; i += 256) {
    float4 v = p[i];
    rb[i] = v;
    float m4 = fmaxf(fmaxf(v.x, v.y), fmaxf(v.z, v.w));
    float mn = fmaxf(m, m4);
    ssum = ssum * __expf(m - mn)
         + __expf(v.x - mn) + __expf(v.y - mn) + __expf(v.z - mn) + __expf(v.w - mn);
    m = mn;
  }
  __shared__ float ms[256], ss[256];
  ms[tid] = m; ss[tid] = ssum; __syncthreads();
  #pragma unroll
  for (int off = 128; off; off >>= 1) {
    if (tid < off) {
      float m2 = fmaxf(ms[tid], ms[tid+off]);
      ss[tid] = ss[tid]*__expf(ms[tid]-m2) + ss[tid+off]*__expf(ms[tid+off]-m2);
      ms[tid] = m2;
    }
    __syncthreads();
  }
  float M = ms[0];
  float inv = 1.0f / ss[0];
  for (int i = tid; i < 8000; i += 256) {
    float4 v = rb[i];
    v.x = __expf(v.x - M) * inv; v.y = __expf(v.y - M) * inv;
    v.z = __expf(v.z - M) * inv; v.w = __expf(v.w - M) * inv;
    p[i] = v;
  }
}

// ---------------- host ----------------

extern "C" void kernel_launch(void* const* d_in, const int* in_sizes, int n_in,
                              void* d_out, int out_size, void* d_ws, size_t ws_size,
                              hipStream_t stream){
  const float* yts   = (const float*)d_in[0];
  const float* enc_h = (const float*)d_in[1];
  const int*   tgt   = (const int*)d_in[2];
  const float* emb   = (const float*)d_in[3];
  const float* ayi_w = (const float*)d_in[6];
  const float* aw_w  = (const float*)d_in[8];
  const float* wf_w = (const float*)d_in[10]; const float* wf_b = (const float*)d_in[11];
  const float* uf_w = (const float*)d_in[12]; const float* uf_b = (const float*)d_in[13];
  const float* wi_w = (const float*)d_in[14]; const float* wi_b = (const float*)d_in[15];
  const float* ui_w = (const float*)d_in[16]; const float* ui_b = (const float*)d_in[17];
  const float* wo_w = (const float*)d_in[18]; const float* wo_b = (const float*)d_in[19];
  const float* uo_w = (const float*)d_in[20]; const float* uo_b = (const float*)d_in[21];
  const float* wc_w = (const float*)d_in[22]; const float* wc_b = (const float*)d_in[23];
  const float* uc_w = (const float*)d_in[24]; const float* uc_b = (const float*)d_in[25];
  const float* xh_w = (const float*)d_in[26]; const float* xh_b = (const float*)d_in[27];
  const float* cls_w= (const float*)d_in[28]; const float* cls_b= (const float*)d_in[29];

  float* out = (float*)d_out;
  float* outAttn = out + (size_t)B_ * T_ * V_;

  char* wsb = (char*)d_ws;
  size_t off = 0;
  auto alloc = [&](size_t bytes)->char*{
    char* p = wsb + off; off += (bytes + 255) & ~(size_t)255; return p;
  };
  ushort* clsT  = (ushort*)alloc((size_t)V_ * 1024 * 2);
  ushort* xhT   = (ushort*)alloc((size_t)1024 * 1024 * 2);
  ushort* WcatT = (ushort*)alloc((size_t)4096 * 1024 * 2);
  ushort* UcatT = (ushort*)alloc((size_t)4096 * 1024 * 2);
  float*  biasU = (float*)alloc(4096 * 4);
  float*  vvec  = (float*)alloc(S_ * 4);
  float*  scores= (float*)alloc(B_ * SE_ * 4);
  float*  attnw = (float*)alloc(B_ * SE_ * 4);
  float*  ctx   = (float*)alloc(B_ * S_ * 4);
  uint*   ready = (uint*)alloc(8 * 64 * 4);
  uint*   cnt   = (uint*)alloc(256);
  ushort* Xb    = (ushort*)alloc((size_t)4096 * 1024 * 2);
  ushort* preb  = (ushort*)alloc((size_t)4096 * 4096 * 2);
  ushort* Hgs   = (ushort*)alloc((65ull + 7ull*8ull) * HSLOT * 2);  // ~15.9 MB
  if (off > ws_size) return;
  ushort* Zb = Xb; // Xb dead after pre-GEMM; reuse for Z

  dim3 tb(32, 8);
  k_transcvt<<<dim3(V_/32, 32), tb, 0, stream>>>(cls_w, clsT, 1024, V_);
  k_transcvt<<<dim3(32, 32), tb, 0, stream>>>(xh_w, xhT, 1024, 1024);
  k_transcvt<<<dim3(32, 32), tb, 0, stream>>>(wf_w, WcatT + 0u*1048576u, 1024, 1024);
  k_transcvt<<<dim3(32, 32), tb, 0, stream>>>(wi_w, WcatT + 1u*1048576u, 1024, 1024);
  k_transcvt<<<dim3(32, 32), tb, 0, stream>>>(wo_w, WcatT + 2u*1048576u, 1024, 1024);
  k_transcvt<<<dim3(32, 32), tb, 0, stream>>>(wc_w, WcatT + 3u*1048576u, 1024, 1024);
  k_transcvt<<<dim3(32, 32), tb, 0, stream>>>(uf_w, UcatT + 0u*1048576u, 1024, 1024);
  k_transcvt<<<dim3(32, 32), tb, 0, stream>>>(ui_w, UcatT + 1u*1048576u, 1024, 1024);
  k_transcvt<<<dim3(32, 32), tb, 0, stream>>>(uo_w, UcatT + 2u*1048576u, 1024, 1024);
  k_transcvt<<<dim3(32, 32), tb, 0, stream>>>(uc_w, UcatT + 3u*1048576u, 1024, 1024);
  k_packbias<<<16, 256, 0, stream>>>(wf_b, wi_b, wo_b, wc_b, uf_b, ui_b, uo_b, uc_b, biasU);
  k_cvtrep<<<64, 256, 0, stream>>>(enc_h, Hgs);
  k_gathercvt<<<4096, 256, 0, stream>>>(emb, tgt, Xb);

  k_attnvec<<<256, 256, 0, stream>>>(ayi_w, aw_w, vvec);
  k_scores<<<2048, 256, 0, stream>>>(yts, vvec, scores);
  k_attn<<<64, 128, 0, stream>>>(scores, attnw, outAttn);
  k_ctx<<<256, 256, 0, stream>>>(yts, attnw, ctx);

  // pre = X @ Ucat + biasU  -> bf16 [4096][4096]
  k_mfma_gemm<2><<<dim3(32, 32), 256, 0, stream>>>(Xb, UcatT, biasU, preb, 4096, 4096);

  // XCD-local replicated recurrence (cooperative for full co-residency)
  hipMemsetAsync(ready, 0, 8 * 64 * 4, stream);
  hipMemsetAsync(cnt, 0, 256, stream);
  {
    void* args[] = { (void*)&WcatT, (void*)&preb, (void*)&ctx, (void*)&Hgs,
                     (void*)&ready, (void*)&cnt };
    hipLaunchCooperativeKernel((void*)k_recur, dim3(256), dim3(512), args, 86016, stream);
  }

  // Z = H @ xh_w + xh_b  -> bf16 [4096][1024]   (H = group-0 slots 1..64)
  k_mfma_gemm<2><<<dim3(8, 32), 256, 0, stream>>>(Hgs + HSLOT, xhT, xh_b, Zb, 4096, 1024);
  // out = Z @ cls_w + cls_b (rows remapped t*64+b -> b*64+t), f32
  k_mfma_gemm<1><<<dim3(V_/128, 32), 256, 0, stream>>>(Zb, clsT, cls_b, out, 4096, V_);
  // single-pass softmax, row staged in LDS
  k_softmaxV<<<4096, 256, 128000, stream>>>(out);
}

// Round 9
// 3108.823 us; speedup vs baseline: 1.3226x; 1.3187x over previous
//
#include <hip/hip_runtime.h>
#include <cstdint>
#include <cstddef>

#define B_  64
#define SE_ 128
#define T_  64
#define S_  1024
#define D_  1024
#define V_  32000
#define HSLOT 65536ull   // one H step: 64*1024 bf16 elems

typedef __attribute__((ext_vector_type(8))) short bhalf8;
typedef __attribute__((ext_vector_type(4))) float floatx4;

__device__ __forceinline__ float sigmoidf_(float x){ return 1.0f/(1.0f+__expf(-x)); }

__device__ __forceinline__ ushort f2bf(float f){
  uint32_t u = __float_as_uint(f);
  uint32_t r = (u + 0x7fffu + ((u >> 16) & 1u)) >> 16;
  return (ushort)r;
}
__device__ __forceinline__ float bf2f(ushort h){ return __uint_as_float(((uint32_t)h) << 16); }

__device__ __forceinline__ void glds16(const ushort* g, ushort* l){
  __builtin_amdgcn_global_load_lds((const __attribute__((address_space(1))) void*)g,
                                   (__attribute__((address_space(3))) void*)l, 16, 0, 0);
}

__device__ __forceinline__ float waveRedSum(float v){
  #pragma unroll
  for (int off = 32; off; off >>= 1) v += __shfl_down(v, off, 64);
  return v;
}

// ---------------- attention path (fp32, small) ----------------

__global__ void k_attnvec(const float* __restrict__ ayi_w, const float* __restrict__ aw_w,
                          float* __restrict__ v){
  int wave = (blockIdx.x * blockDim.x + threadIdx.x) >> 6;
  int lane = threadIdx.x & 63;
  if (wave >= S_) return;
  const float* row = ayi_w + (size_t)wave * S_;
  float acc = 0.f;
  #pragma unroll 4
  for (int s = lane; s < S_; s += 64) acc += row[s] * aw_w[s];
  acc = waveRedSum(acc);
  if (lane == 0) v[wave] = acc;
}

__global__ void k_scores(const float* __restrict__ yts, const float* __restrict__ v,
                         float* __restrict__ scores){
  int wave = (blockIdx.x * blockDim.x + threadIdx.x) >> 6;
  int lane = threadIdx.x & 63;
  const float* row = yts + (size_t)wave * S_;
  float acc = 0.f;
  #pragma unroll 4
  for (int s = lane; s < S_; s += 64) acc += row[s] * v[s];
  acc = waveRedSum(acc);
  if (lane == 0) scores[wave] = acc;
}

__global__ void k_attn(const float* __restrict__ scores, float* __restrict__ attnw,
                       float* __restrict__ outAttn){
  int b = blockIdx.x;
  int e = threadIdx.x;
  __shared__ float sm[128];
  float x = scores[b*SE_ + e];
  sm[e] = x; __syncthreads();
  #pragma unroll
  for (int off = 64; off; off >>= 1){
    if (e < off) sm[e] = fmaxf(sm[e], sm[e+off]);
    __syncthreads();
  }
  float m = sm[0]; __syncthreads();
  float p = __expf(x - m);
  sm[e] = p; __syncthreads();
  #pragma unroll
  for (int off = 64; off; off >>= 1){
    if (e < off) sm[e] += sm[e+off];
    __syncthreads();
  }
  float a = p / sm[0];
  attnw[b*SE_ + e] = a;
  float* dst = outAttn + (size_t)b * T_ * SE_ + e;
  #pragma unroll 4
  for (int t = 0; t < T_; ++t) dst[t*SE_] = a;
}

__global__ void k_ctx(const float* __restrict__ yts, const float* __restrict__ attnw,
                      float* __restrict__ ctx){
  int idx = blockIdx.x * blockDim.x + threadIdx.x;
  int b = idx >> 10, s = idx & (S_-1);
  const float* base = yts + (size_t)b * SE_ * S_ + s;
  const float* a = attnw + b * SE_;
  float acc = 0.f;
  #pragma unroll 8
  for (int e = 0; e < SE_; ++e) acc += a[e] * base[(size_t)e * S_];
  ctx[idx] = acc;
}

// ---------------- conversion / packing ----------------

__global__ void k_transcvt(const float* __restrict__ src, ushort* __restrict__ dst,
                           int K, int N){
  __shared__ float t[32][33];
  int n0 = blockIdx.x * 32, k0 = blockIdx.y * 32;
  for (int r = threadIdx.y; r < 32; r += 8)
    t[r][threadIdx.x] = src[(size_t)(k0 + r) * N + n0 + threadIdx.x];
  __syncthreads();
  for (int r = threadIdx.y; r < 32; r += 8)
    dst[(size_t)(n0 + r) * K + k0 + threadIdx.x] = f2bf(t[threadIdx.x][r]);
}

// enc_h f32 -> bf16, replicated into slot 0 of each XCD group's H buffer
__global__ void k_cvtrep(const float* __restrict__ src, ushort* __restrict__ Hgs){
  int i = blockIdx.x * blockDim.x + threadIdx.x;   // 16384 float4 groups
  float4 v = ((const float4*)src)[i];
  ushort4 o; o.x = f2bf(v.x); o.y = f2bf(v.y); o.z = f2bf(v.z); o.w = f2bf(v.w);
  #pragma unroll
  for (int g = 0; g < 8; ++g) {
    size_t gbase = (g == 0) ? 0ull : (65ull + (size_t)(g-1)*8ull) * HSLOT;
    ((ushort4*)(Hgs + gbase))[i] = o;
  }
}

__global__ void k_gathercvt(const float* __restrict__ emb, const int* __restrict__ tgt,
                            ushort* __restrict__ Xb){
  int r = blockIdx.x;
  int token = tgt[((r & 63) << 6) + (r >> 6)];
  const float4* src = (const float4*)(emb + (size_t)token * D_);
  ushort* dst = Xb + (size_t)r * D_;
  int i = threadIdx.x;
  float4 v = src[i];
  ushort4 o; o.x = f2bf(v.x); o.y = f2bf(v.y); o.z = f2bf(v.z); o.w = f2bf(v.w);
  ((ushort4*)dst)[i] = o;
}

__global__ void k_packbias(const float* __restrict__ wb0, const float* __restrict__ wb1,
                           const float* __restrict__ wb2, const float* __restrict__ wb3,
                           const float* __restrict__ ub0, const float* __restrict__ ub1,
                           const float* __restrict__ ub2, const float* __restrict__ ub3,
                           float* __restrict__ dst){
  int col = blockIdx.x * blockDim.x + threadIdx.x;
  int g = col >> 10, s = col & 1023;
  const float* wb = (g==0) ? wb0 : (g==1) ? wb1 : (g==2) ? wb2 : wb3;
  const float* ub = (g==0) ? ub0 : (g==1) ? ub1 : (g==2) ? ub2 : ub3;
  dst[col] = wb[s] + ub[s];
}

// ---------------- bf16 MFMA GEMM (m97 structure + XCD-chunked swizzle) ----------------
template<int OUT_MODE>
__global__ __launch_bounds__(256) void k_mfma_gemm(
    const ushort* __restrict__ A, const ushort* __restrict__ BT,
    const float* __restrict__ bias, void* __restrict__ C, int M, int N)
{
  __shared__ ushort As[128*32];
  __shared__ ushort Bs[128*32];
  const int tid = threadIdx.x;
  const int lane = tid & 63, w = tid >> 6;
  const int nwg = gridDim.x * gridDim.y;
  const int L = blockIdx.y * gridDim.x + blockIdx.x;
  const int logical = (L & 7) * (nwg >> 3) + (L >> 3);
  const int by = logical / gridDim.x;
  const int bx = logical - by * gridDim.x;
  const int m0 = by * 128, n0 = bx * 128;
  const int wr = (w >> 1) * 64, wc = (w & 1) * 64;

  const int cr = (lane >> 2);
  const int ck = (lane & 3) * 8;
  const ushort* gA0 = A  + (size_t)(m0 + (2*w)*16   + cr) * 1024 + ck;
  const ushort* gA1 = A  + (size_t)(m0 + (2*w+1)*16 + cr) * 1024 + ck;
  const ushort* gB0 = BT + (size_t)(n0 + (2*w)*16   + cr) * 1024 + ck;
  const ushort* gB1 = BT + (size_t)(n0 + (2*w+1)*16 + cr) * 1024 + ck;
  ushort* lA0 = As + (2*w)*512;   ushort* lA1 = As + (2*w+1)*512;
  ushort* lB0 = Bs + (2*w)*512;   ushort* lB1 = Bs + (2*w+1)*512;

  floatx4 acc[4][4] = {};

  for (int kt = 0; kt < 1024; kt += 32) {
    glds16(gA0 + kt, lA0); glds16(gA1 + kt, lA1);
    glds16(gB0 + kt, lB0); glds16(gB1 + kt, lB1);
    __syncthreads();
    bhalf8 a[4], b[4];
    #pragma unroll
    for (int f = 0; f < 4; ++f) {
      a[f] = *(const bhalf8*)&As[(wr + f*16 + (lane & 15)) * 32 + (lane >> 4) * 8];
      b[f] = *(const bhalf8*)&Bs[(wc + f*16 + (lane & 15)) * 32 + (lane >> 4) * 8];
    }
    #pragma unroll
    for (int i = 0; i < 4; ++i)
      #pragma unroll
      for (int j = 0; j < 4; ++j)
        acc[i][j] = __builtin_amdgcn_mfma_f32_16x16x32_bf16(a[i], b[j], acc[i][j], 0, 0, 0);
    __syncthreads();
  }

  const int crow = (lane >> 4) * 4, ccol = lane & 15;
  #pragma unroll
  for (int i = 0; i < 4; ++i) {
    #pragma unroll
    for (int j = 0; j < 4; ++j) {
      int row = m0 + wr + i*16 + crow;
      int col = n0 + wc + j*16 + ccol;
      float bv = bias ? bias[col] : 0.f;
      #pragma unroll
      for (int r = 0; r < 4; ++r) {
        float v = acc[i][j][r] + bv;
        if (OUT_MODE == 0) {
          ((float*)C)[(size_t)(row + r) * N + col] = v;
        } else if (OUT_MODE == 1) {
          int rr = row + r;
          ((float*)C)[(size_t)(((rr & 63) << 6) + (rr >> 6)) * N + col] = v;
        } else {
          ((ushort*)C)[(size_t)(row + r) * N + col] = f2bf(v);
        }
      }
    }
  }
}

// ---------------- XCD-local replicated recurrence + MFMA-heater busy-wait ------------
// Identical to round 8 EXCEPT the wait loop: no s_sleep, all 8 waves poll, and between
// polls each wave runs a dense burst of dummy MFMAs (4 independent chains on the
// VGPR-resident W fragments). Purpose: keep the CUs hot so DVFS doesn't drop SCLK to
// the idle floor during the handoff — the theory is that the mechanism-invariant
// ~47us/step of rounds 3-8 is a ~3us critical path executed at idle clocks.
__global__ __launch_bounds__(512) void k_recur(
    const ushort* __restrict__ WT, const ushort* __restrict__ preb,
    const float* __restrict__ ctx, ushort* __restrict__ Hgs,
    uint* __restrict__ ready, uint* __restrict__ cnt)
{
  extern __shared__ char smem[];
  float* gbuf = (float*)smem;                  // [64][132] f32 = 33792 B
  __shared__ uint sgrp, srank;
  const int tid = threadIdx.x, lane = tid & 63, w = tid >> 6;

  if (tid == 0) {
    uint xcc;
    asm volatile("s_getreg_b32 %0, hwreg(HW_REG_XCC_ID, 0, 32)" : "=s"(xcc));
    xcc &= 7u;
    sgrp = xcc;
    srank = atomicAdd(&cnt[xcc], 1u) & 31u;
  }
  __syncthreads();
  const int grp = (int)sgrp, r = (int)srank;
  const size_t gbase = (grp == 0) ? 0ull : (65ull + (size_t)(grp-1)*8ull) * HSLOT;

  // ---- W columns into VGPRs: wave w -> gate g=w>>1, 16-col half s16=w&1 ----
  const int gate = w >> 1, s16 = w & 1;
  const int colg = (gate << 10) + (r << 5) + (s16 << 4) + (lane & 15); // WT row
  const ushort* wrow = WT + ((size_t)colg << 10) + ((lane >> 4) << 3);
  bhalf8 wfrag[32];
  #pragma unroll
  for (int kk = 0; kk < 32; ++kk)
    wfrag[kk] = *(const bhalf8*)(wrow + kk*32);

  // pointwise cell assignment: thread -> (b, 4 consecutive s)
  const int pb = tid >> 3;
  const int sl4 = (tid & 7) << 2;
  const float4 ctx4 = *(const float4*)(ctx + (pb << 10) + (r << 5) + sl4);

  const int arow = lane & 15;
  const int aoff = (lane >> 4) << 3;
  const int colw = (w << 4) + (lane & 15);     // gbuf col 0..127
  uint* myflags = ready + grp * 64;

  #pragma unroll 1
  for (int t = 0; t < 64; ++t) {
    // pre-activation loads (independent of H) — overlap the wait
    const ushort* prow = preb + (((size_t)(t*64 + pb)) << 12) + (r << 5) + sl4;
    ushort4 pf = *(const ushort4*)(prow);
    ushort4 pi = *(const ushort4*)(prow + 1024);
    ushort4 po = *(const ushort4*)(prow + 2048);
    ushort4 pc = *(const ushort4*)(prow + 3072);

    // wait for this XCD's H[t]: ALL waves poll; dummy-MFMA heater between polls
    if (t > 0) {
      const uint need = (uint)t;
      floatx4 j0 = {}, j1 = {}, j2 = {}, j3 = {};
      for (;;) {
        uint v = __hip_atomic_load(myflags + (lane & 31), __ATOMIC_RELAXED,
                                   __HIP_MEMORY_SCOPE_AGENT);
        if (__all(v >= need)) break;
        #pragma unroll
        for (int hh = 0; hh < 8; ++hh) {
          j0 = __builtin_amdgcn_mfma_f32_16x16x32_bf16(wfrag[hh],    wfrag[hh+8],  j0, 0,0,0);
          j1 = __builtin_amdgcn_mfma_f32_16x16x32_bf16(wfrag[hh+8],  wfrag[hh+16], j1, 0,0,0);
          j2 = __builtin_amdgcn_mfma_f32_16x16x32_bf16(wfrag[hh+16], wfrag[hh+24], j2, 0,0,0);
          j3 = __builtin_amdgcn_mfma_f32_16x16x32_bf16(wfrag[hh+24], wfrag[hh],    j3, 0,0,0);
        }
      }
      asm volatile("" :: "v"(j0[0]), "v"(j1[0]), "v"(j2[0]), "v"(j3[0]));
      __syncthreads();
      asm volatile("" ::: "memory");
    }

    // GEMM: C[64 rows][16 cols] per wave, full K=1024 from VGPR-resident W
    const ushort* Hrd = Hgs + gbase + (size_t)(grp == 0 ? t : (t & 7)) * HSLOT;
    floatx4 acc[4] = {};
    #pragma unroll
    for (int kk = 0; kk < 32; ++kk) {
      #pragma unroll
      for (int i = 0; i < 4; ++i) {
        bhalf8 a = *(const bhalf8*)(Hrd + ((i*16 + arow) << 10) + kk*32 + aoff);
        acc[i] = __builtin_amdgcn_mfma_f32_16x16x32_bf16(a, wfrag[kk], acc[i], 0, 0, 0);
      }
    }

    // exchange gates through LDS (each cell written exactly once, no atomics)
    #pragma unroll
    for (int i = 0; i < 4; ++i) {
      #pragma unroll
      for (int rr = 0; rr < 4; ++rr)
        gbuf[(i*16 + ((lane >> 4) << 2) + rr)*132 + colw] = acc[i][rr];
    }
    __syncthreads();

    // fused pointwise LSTM cell (4 cells/thread); plain store to local H[t+1]
    {
      const float* gb = gbuf + pb*132;
      float h[4];
      const ushort* pfp = (const ushort*)&pf; const ushort* pip = (const ushort*)&pi;
      const ushort* pop = (const ushort*)&po; const ushort* pcp = (const ushort*)&pc;
      const float* cxp = (const float*)&ctx4;
      #pragma unroll
      for (int c = 0; c < 4; ++c) {
        float fv = gb[      sl4 + c] + bf2f(pfp[c]);
        float iv = gb[32  + sl4 + c] + bf2f(pip[c]);
        float ov = gb[64  + sl4 + c] + bf2f(pop[c]);
        float cv = gb[96  + sl4 + c] + bf2f(pcp[c]);
        float ct = sigmoidf_(fv) * cxp[c] + sigmoidf_(iv) * tanhf(cv);
        h[c] = sigmoidf_(ov) * tanhf(ct);
      }
      ushort4 hv; hv.x = f2bf(h[0]); hv.y = f2bf(h[1]); hv.z = f2bf(h[2]); hv.w = f2bf(h[3]);
      ushort* Hwr = Hgs + gbase + (size_t)(grp == 0 ? (t+1) : ((t+1) & 7)) * HSLOT;
      *(ushort4*)(Hwr + (pb << 10) + (r << 5) + sl4) = hv;
    }
    __syncthreads();   // drains vmcnt(0): H stores are in the local L2
    if (tid == 0)
      __hip_atomic_store(myflags + r, (uint)(t + 1), __ATOMIC_RELAXED,
                         __HIP_MEMORY_SCOPE_AGENT);
  }
}

// ---------------- single-pass row softmax over V=32000 (row staged in LDS) ----------------
__global__ __launch_bounds__(256) void k_softmaxV(float* __restrict__ out){
  extern __shared__ float rowbuf[];
  int r = blockIdx.x;
  float4* p = (float4*)(out + (size_t)r * V_);
  float4* rb = (float4*)rowbuf;
  int tid = threadIdx.x;
  float m = -1e30f, ssum = 0.f;
  for (int i = tid; i < 8000; i += 256) {
    float4 v = p[i];
    rb[i] = v;
    float m4 = fmaxf(fmaxf(v.x, v.y), fmaxf(v.z, v.w));
    float mn = fmaxf(m, m4);
    ssum = ssum * __expf(m - mn)
         + __expf(v.x - mn) + __expf(v.y - mn) + __expf(v.z - mn) + __expf(v.w - mn);
    m = mn;
  }
  __shared__ float ms[256], ss[256];
  ms[tid] = m; ss[tid] = ssum; __syncthreads();
  #pragma unroll
  for (int off = 128; off; off >>= 1) {
    if (tid < off) {
      float m2 = fmaxf(ms[tid], ms[tid+off]);
      ss[tid] = ss[tid]*__expf(ms[tid]-m2) + ss[tid+off]*__expf(ms[tid+off]-m2);
      ms[tid] = m2;
    }
    __syncthreads();
  }
  float M = ms[0];
  float inv = 1.0f / ss[0];
  for (int i = tid; i < 8000; i += 256) {
    float4 v = rb[i];
    v.x = __expf(v.x - M) * inv; v.y = __expf(v.y - M) * inv;
    v.z = __expf(v.z - M) * inv; v.w = __expf(v.w - M) * inv;
    p[i] = v;
  }
}

// ---------------- host ----------------

extern "C" void kernel_launch(void* const* d_in, const int* in_sizes, int n_in,
                              void* d_out, int out_size, void* d_ws, size_t ws_size,
                              hipStream_t stream){
  const float* yts   = (const float*)d_in[0];
  const float* enc_h = (const float*)d_in[1];
  const int*   tgt   = (const int*)d_in[2];
  const float* emb   = (const float*)d_in[3];
  const float* ayi_w = (const float*)d_in[6];
  const float* aw_w  = (const float*)d_in[8];
  const float* wf_w = (const float*)d_in[10]; const float* wf_b = (const float*)d_in[11];
  const float* uf_w = (const float*)d_in[12]; const float* uf_b = (const float*)d_in[13];
  const float* wi_w = (const float*)d_in[14]; const float* wi_b = (const float*)d_in[15];
  const float* ui_w = (const float*)d_in[16]; const float* ui_b = (const float*)d_in[17];
  const float* wo_w = (const float*)d_in[18]; const float* wo_b = (const float*)d_in[19];
  const float* uo_w = (const float*)d_in[20]; const float* uo_b = (const float*)d_in[21];
  const float* wc_w = (const float*)d_in[22]; const float* wc_b = (const float*)d_in[23];
  const float* uc_w = (const float*)d_in[24]; const float* uc_b = (const float*)d_in[25];
  const float* xh_w = (const float*)d_in[26]; const float* xh_b = (const float*)d_in[27];
  const float* cls_w= (const float*)d_in[28]; const float* cls_b= (const float*)d_in[29];

  float* out = (float*)d_out;
  float* outAttn = out + (size_t)B_ * T_ * V_;

  char* wsb = (char*)d_ws;
  size_t off = 0;
  auto alloc = [&](size_t bytes)->char*{
    char* p = wsb + off; off += (bytes + 255) & ~(size_t)255; return p;
  };
  ushort* clsT  = (ushort*)alloc((size_t)V_ * 1024 * 2);
  ushort* xhT   = (ushort*)alloc((size_t)1024 * 1024 * 2);
  ushort* WcatT = (ushort*)alloc((size_t)4096 * 1024 * 2);
  ushort* UcatT = (ushort*)alloc((size_t)4096 * 1024 * 2);
  float*  biasU = (float*)alloc(4096 * 4);
  float*  vvec  = (float*)alloc(S_ * 4);
  float*  scores= (float*)alloc(B_ * SE_ * 4);
  float*  attnw = (float*)alloc(B_ * SE_ * 4);
  float*  ctx   = (float*)alloc(B_ * S_ * 4);
  uint*   ready = (uint*)alloc(8 * 64 * 4);
  uint*   cnt   = (uint*)alloc(256);
  ushort* Xb    = (ushort*)alloc((size_t)4096 * 1024 * 2);
  ushort* preb  = (ushort*)alloc((size_t)4096 * 4096 * 2);
  ushort* Hgs   = (ushort*)alloc((65ull + 7ull*8ull) * HSLOT * 2);  // ~15.9 MB
  if (off > ws_size) return;
  ushort* Zb = Xb; // Xb dead after pre-GEMM; reuse for Z

  dim3 tb(32, 8);
  k_transcvt<<<dim3(V_/32, 32), tb, 0, stream>>>(cls_w, clsT, 1024, V_);
  k_transcvt<<<dim3(32, 32), tb, 0, stream>>>(xh_w, xhT, 1024, 1024);
  k_transcvt<<<dim3(32, 32), tb, 0, stream>>>(wf_w, WcatT + 0u*1048576u, 1024, 1024);
  k_transcvt<<<dim3(32, 32), tb, 0, stream>>>(wi_w, WcatT + 1u*1048576u, 1024, 1024);
  k_transcvt<<<dim3(32, 32), tb, 0, stream>>>(wo_w, WcatT + 2u*1048576u, 1024, 1024);
  k_transcvt<<<dim3(32, 32), tb, 0, stream>>>(wc_w, WcatT + 3u*1048576u, 1024, 1024);
  k_transcvt<<<dim3(32, 32), tb, 0, stream>>>(uf_w, UcatT + 0u*1048576u, 1024, 1024);
  k_transcvt<<<dim3(32, 32), tb, 0, stream>>>(ui_w, UcatT + 1u*1048576u, 1024, 1024);
  k_transcvt<<<dim3(32, 32), tb, 0, stream>>>(uo_w, UcatT + 2u*1048576u, 1024, 1024);
  k_transcvt<<<dim3(32, 32), tb, 0, stream>>>(uc_w, UcatT + 3u*1048576u, 1024, 1024);
  k_packbias<<<16, 256, 0, stream>>>(wf_b, wi_b, wo_b, wc_b, uf_b, ui_b, uo_b, uc_b, biasU);
  k_cvtrep<<<64, 256, 0, stream>>>(enc_h, Hgs);
  k_gathercvt<<<4096, 256, 0, stream>>>(emb, tgt, Xb);

  k_attnvec<<<256, 256, 0, stream>>>(ayi_w, aw_w, vvec);
  k_scores<<<2048, 256, 0, stream>>>(yts, vvec, scores);
  k_attn<<<64, 128, 0, stream>>>(scores, attnw, outAttn);
  k_ctx<<<256, 256, 0, stream>>>(yts, attnw, ctx);

  // pre = X @ Ucat + biasU  -> bf16 [4096][4096]
  k_mfma_gemm<2><<<dim3(32, 32), 256, 0, stream>>>(Xb, UcatT, biasU, preb, 4096, 4096);

  // XCD-local replicated recurrence + heater busy-wait (cooperative for co-residency)
  hipMemsetAsync(ready, 0, 8 * 64 * 4, stream);
  hipMemsetAsync(cnt, 0, 256, stream);
  {
    void* args[] = { (void*)&WcatT, (void*)&preb, (void*)&ctx, (void*)&Hgs,
                     (void*)&ready, (void*)&cnt };
    hipLaunchCooperativeKernel((void*)k_recur, dim3(256), dim3(512), args, 86016, stream);
  }

  // Z = H @ xh_w + xh_b  -> bf16 [4096][1024]   (H = group-0 slots 1..64)
  k_mfma_gemm<2><<<dim3(8, 32), 256, 0, stream>>>(Hgs + HSLOT, xhT, xh_b, Zb, 4096, 1024);
  // out = Z @ cls_w + cls_b (rows remapped t*64+b -> b*64+t), f32
  k_mfma_gemm<1><<<dim3(V_/128, 32), 256, 0, stream>>>(Zb, clsT, cls_b, out, 4096, V_);
  // single-pass softmax, row staged in LDS
  k_softmaxV<<<4096, 256, 128000, stream>>>(out);
}